// Round 15
// baseline (108.578 us; speedup 1.0000x reference)
//
#include <hip/hip_runtime.h>
#include <hip/hip_bf16.h>
#include <hip/hip_fp8.h>
#include <math.h>

typedef float f32x4 __attribute__((ext_vector_type(4)));
typedef int   i32x4 __attribute__((ext_vector_type(4)));
typedef int   v8i   __attribute__((ext_vector_type(8)));

constexpr int Nn = 8192;   // B*S
constexpr int Dd = 256;    // feature dim (== bytes per fp8 row)
constexpr float LOG2E     = 1.4426950408889634f;
constexpr float SIM_SCALE = 20.0f * LOG2E;   // (1/tau)*log2(e), tau=0.05
constexpr float SIM_BIAS  = -20.0f * LOG2E;  // fixed max = 1/tau (|q.k|<=1)
constexpr int   SCALE1    = 0x7F7F7F7F;      // E8M0 127 = 2^0 in every byte

// async global->LDS DMA, 16B/lane; LDS dst = wave-uniform base + lane*16.
// (R5/R11-R14-verified path.)
typedef __attribute__((address_space(1))) const unsigned int gu32;
typedef __attribute__((address_space(3))) unsigned int lu32;
__device__ __forceinline__ void gload16(const unsigned char* g, unsigned char* l) {
  __builtin_amdgcn_global_load_lds((gu32*)(uintptr_t)g, (lu32*)(uintptr_t)l, 16, 0, 0);
}

// ---------------------------------------------------------------------------
// Kernel 1: L2-normalize rows -> fp8 e4m3 (plain layout; the scaled MFMA's
// operand is 32 contiguous K-bytes per lane); init cbias / g_all / g_pos.
// ---------------------------------------------------------------------------
__global__ __launch_bounds__(256) void prep_kernel(const float* __restrict__ logits,
                                                   const float* __restrict__ labels,
                                                   const int* __restrict__ pad,
                                                   unsigned char* __restrict__ qb,
                                                   unsigned char* __restrict__ kb,
                                                   float* __restrict__ cbias,
                                                   float* __restrict__ g_all,
                                                   float* __restrict__ g_pos) {
  const int j = blockIdx.x * 256 + threadIdx.x;
  if (j < Nn) {
    cbias[j] = pad[j] ? 0.0f : -1e30f;
    g_all[j] = 0.0f;
    g_pos[j] = 0.0f;
  }

  const int gw   = (blockIdx.x * 256 + threadIdx.x) >> 6;
  const int lane = threadIdx.x & 63;
  const float* src;
  unsigned char* dst;
  int row;
  if (gw < Nn) { src = logits; dst = qb; row = gw; }
  else         { src = labels; dst = kb; row = gw - Nn; }

  const float4 v = *reinterpret_cast<const float4*>(src + (size_t)row * Dd + lane * 4);
  float ss = v.x * v.x + v.y * v.y + v.z * v.z + v.w * v.w;
#pragma unroll
  for (int m = 32; m >= 1; m >>= 1) ss += __shfl_xor(ss, m);
  const float scale = 1.0f / fmaxf(sqrtf(ss), 1e-12f);

  const __hip_fp8_e4m3 e0(v.x * scale);
  const __hip_fp8_e4m3 e1(v.y * scale);
  const __hip_fp8_e4m3 e2(v.z * scale);
  const __hip_fp8_e4m3 e3(v.w * scale);
  const unsigned int packed = (unsigned int)e0.__x |
                              ((unsigned int)e1.__x << 8) |
                              ((unsigned int)e2.__x << 16) |
                              ((unsigned int)e3.__x << 24);
  reinterpret_cast<unsigned int*>(dst + (size_t)row * Dd)[lane] = packed;
}

// ---------------------------------------------------------------------------
// Kernel 2: fused sim = Q K^T / tau + dual exp-sum epilogue, fp8 MX-MFMA.
// R14 structure with ONE change: 128x256 block tile (wave = 64x128, c[4][8]).
// reads/MFMA 1.0 -> 0.75, staging DMAs -25%, block count halved (half the
// barrier-drain events); occupancy unchanged (VGPR-bound 2 waves/SIMD).
// Epilogue partial-plane geometry identical (2 waves per row-half -> 32
// partials/row). A-staging constants byte-identical to R14; B over 8 iters.
// ---------------------------------------------------------------------------
__global__ __launch_bounds__(256) void gemm_lse_kernel(const unsigned char* __restrict__ qb,
                                                       const unsigned char* __restrict__ kb,
                                                       const float* __restrict__ cbias,
                                                       const int* __restrict__ ad,
                                                       float* __restrict__ g_all,
                                                       float* __restrict__ g_pos) {
  __shared__ unsigned char smem[49152];  // As(16K) | Bs(32K); epilogue reuse
  unsigned char* As = smem;
  unsigned char* Bs = smem + 16384;
  float* redA = reinterpret_cast<float*>(smem);         // 128 x 32 partials
  float* redP = reinterpret_cast<float*>(smem) + 4096;  // 128 x 32 partials

  const int tid  = threadIdx.x;
  const int lane = tid & 63;
  const int w    = tid >> 6;
  const int wrow = (w >> 1) * 64;
  const int wcol = (w & 1) * 128;
  const int lq   = lane & 15;
  const int qd   = lane >> 4;
  const int rowBase = blockIdx.x * 128;
  const int colBase = blockIdx.y * 256;

  // staging constants (verified): lane l -> row +(l>>3), 16B group (l&7)^(l>>3)
  const int srl = lane >> 3;
  const int cg  = (lane & 7) ^ srl;
  const unsigned char* gA0 = qb + (size_t)(rowBase + w * 32 + srl) * Dd + cg * 16;
  const unsigned char* gB0 = kb + (size_t)(colBase + w * 64 + srl) * Dd + cg * 16;

  f32x4 c[4][8];
#pragma unroll
  for (int mt = 0; mt < 4; ++mt)
#pragma unroll
    for (int nt = 0; nt < 8; ++nt)
      c[mt][nt] = (f32x4){0.f, 0.f, 0.f, 0.f};

  for (int kk = 0; kk < 2; ++kk) {
    const int kOff = kk * 128;  // byte offset into the 256 B row
    __syncthreads();  // prior MFMA phase done reading LDS
#pragma unroll
    for (int i = 0; i < 4; ++i)   // A: 128 rows, wave covers w*32 .. +32
      gload16(gA0 + (size_t)i * 8 * Dd + kOff, &As[(w * 32 + i * 8) * 128]);
#pragma unroll
    for (int i = 0; i < 8; ++i)   // B: 256 rows, wave covers w*64 .. +64
      gload16(gB0 + (size_t)i * 8 * Dd + kOff, &Bs[(w * 64 + i * 8) * 128]);
    __syncthreads();  // drains vmcnt (DMA) before fragment reads

    const int g0 = qd << 1;  // lane's first 16B group (K bytes qd*32..+15)
    v8i af[4];
#pragma unroll
    for (int mt = 0; mt < 4; ++mt) {
      const int r = wrow + mt * 16 + lq;
      const i32x4 lo = *reinterpret_cast<const i32x4*>(&As[r * 128 + ((g0 ^ (r & 7)) << 4)]);
      const i32x4 hi = *reinterpret_cast<const i32x4*>(&As[r * 128 + (((g0 + 1) ^ (r & 7)) << 4)]);
      af[mt] = (v8i){lo.x, lo.y, lo.z, lo.w, hi.x, hi.y, hi.z, hi.w};
    }
#pragma unroll
    for (int nt = 0; nt < 8; ++nt) {
      const int r = wcol + nt * 16 + lq;
      const i32x4 lo = *reinterpret_cast<const i32x4*>(&Bs[r * 128 + ((g0 ^ (r & 7)) << 4)]);
      const i32x4 hi = *reinterpret_cast<const i32x4*>(&Bs[r * 128 + (((g0 + 1) ^ (r & 7)) << 4)]);
      const v8i bfq = (v8i){lo.x, lo.y, lo.z, lo.w, hi.x, hi.y, hi.z, hi.w};
#pragma unroll
      for (int mt = 0; mt < 4; ++mt)
        c[mt][nt] = __builtin_amdgcn_mfma_scale_f32_16x16x128_f8f6f4(
            af[mt], bfq, c[mt][nt], 0, 0, 0, SCALE1, 0, SCALE1);
    }
  }

  // ---- epilogue: e = exp(sim-20); pos gated by ad match ----
  float colB[8];
  int colAd[8];
#pragma unroll
  for (int nt = 0; nt < 8; ++nt) {
    const int col = colBase + wcol + nt * 16 + lq;
    colB[nt]  = SIM_BIAS + cbias[col];
    colAd[nt] = ad[col];
  }

  __syncthreads();  // all waves done with As/Bs before reuse as partials

  const int idx = (w & 1) * 16 + lq;   // 32 partials per row (2 waves/row-half)
  const int g   = idx >> 2;
  const int gi  = idx & 3;

#pragma unroll
  for (int mt = 0; mt < 4; ++mt) {
#pragma unroll
    for (int r = 0; r < 4; ++r) {
      const int row   = wrow + mt * 16 + qd * 4 + r;
      const int rowAd = ad[rowBase + row];
      float a = 0.f, p = 0.f;
#pragma unroll
      for (int nt = 0; nt < 8; ++nt) {
        const float e = __builtin_amdgcn_exp2f(fmaf(c[mt][nt][r], SIM_SCALE, colB[nt]));
        a += e;
        p += (colAd[nt] == rowAd) ? e : 0.f;
      }
      const int off = row * 32 + ((g ^ (row & 7)) << 2) + gi;
      redA[off] = a;
      redP[off] = p;
    }
  }
  __syncthreads();

  if (tid < 128) {
    const int row = tid;
    float a = 0.f, p = 0.f;
#pragma unroll
    for (int gg = 0; gg < 8; ++gg) {
      const int off = row * 32 + ((gg ^ (row & 7)) << 2);
      const f32x4 va = *reinterpret_cast<const f32x4*>(&redA[off]);
      const f32x4 vp = *reinterpret_cast<const f32x4*>(&redP[off]);
      a += (va[0] + va[1]) + (va[2] + va[3]);
      p += (vp[0] + vp[1]) + (vp[2] + vp[3]);
    }
    atomicAdd(&g_all[rowBase + row], a);
    atomicAdd(&g_pos[rowBase + row], p);
  }
}

// ---------------------------------------------------------------------------
// Kernel 3: loss = mean over valid rows of log(g_all) - log(g_pos).
// ---------------------------------------------------------------------------
__global__ __launch_bounds__(1024) void reduce_kernel(const float* __restrict__ g_all,
                                                      const float* __restrict__ g_pos,
                                                      const int* __restrict__ pad,
                                                      float* __restrict__ out) {
  __shared__ float sS[16], sC[16];
  const int t = threadIdx.x;
  float s = 0.f, c = 0.f;
  const float4* ga4 = (const float4*)g_all;
  const float4* gp4 = (const float4*)g_pos;
  const int4*   pd4 = (const int4*)pad;
  for (int i = t; i < Nn / 4; i += 1024) {
    const float4 ga = ga4[i];
    const float4 gp = gp4[i];
    const int4   pd = pd4[i];
    if (pd.x) { s += __logf(ga.x) - __logf(gp.x); c += 1.f; }
    if (pd.y) { s += __logf(ga.y) - __logf(gp.y); c += 1.f; }
    if (pd.z) { s += __logf(ga.z) - __logf(gp.z); c += 1.f; }
    if (pd.w) { s += __logf(ga.w) - __logf(gp.w); c += 1.f; }
  }
#pragma unroll
  for (int m = 32; m >= 1; m >>= 1) {
    s += __shfl_xor(s, m);
    c += __shfl_xor(c, m);
  }
  if ((t & 63) == 0) { sS[t >> 6] = s; sC[t >> 6] = c; }
  __syncthreads();
  if (t == 0) {
    float S = 0.f, C = 0.f;
#pragma unroll
    for (int i = 0; i < 16; ++i) { S += sS[i]; C += sC[i]; }
    out[0] = S / fmaxf(C, 1.0f);
  }
}

extern "C" void kernel_launch(void* const* d_in, const int* in_sizes, int n_in,
                              void* d_out, int out_size, void* d_ws, size_t ws_size,
                              hipStream_t stream) {
  const float* logits = (const float*)d_in[0];
  const float* labels = (const float*)d_in[1];
  const int*   pad    = (const int*)d_in[2];
  const int*   ad     = (const int*)d_in[3];

  char* ws = (char*)d_ws;
  unsigned char* qb = (unsigned char*)(ws);             // 2 MiB (fp8)
  unsigned char* kb = (unsigned char*)(ws + 2097152);   // 2 MiB (fp8)
  float*  cb   = (float*)(ws + 4194304);                // 32 KiB
  float*  gAll = (float*)(ws + 4227072);                // 32 KiB
  float*  gPos = (float*)(ws + 4259840);                // 32 KiB
  float*  out  = (float*)d_out;

  prep_kernel<<<4096, 256, 0, stream>>>(logits, labels, pad, qb, kb, cb, gAll, gPos);
  gemm_lse_kernel<<<dim3(64, 32), 256, 0, stream>>>(qb, kb, cb, ad, gAll, gPos);
  reduce_kernel<<<1, 1024, 0, stream>>>(gAll, gPos, pad, out);
}

// Round 16
// 103.882 us; speedup vs baseline: 1.0452x; 1.0452x over previous
//
#include <hip/hip_runtime.h>
#include <hip/hip_bf16.h>
#include <hip/hip_fp8.h>
#include <math.h>

typedef float f32x4 __attribute__((ext_vector_type(4)));
typedef int   i32x4 __attribute__((ext_vector_type(4)));
typedef int   v8i   __attribute__((ext_vector_type(8)));

constexpr int Nn = 8192;   // B*S
constexpr int Dd = 256;    // feature dim (== bytes per fp8 row)
constexpr float LOG2E     = 1.4426950408889634f;
constexpr float SIM_SCALE = 20.0f * LOG2E;   // (1/tau)*log2(e), tau=0.05
constexpr float SIM_BIAS  = -20.0f * LOG2E;  // fixed max = 1/tau (|q.k|<=1)
constexpr int   SCALE1    = 0x7F7F7F7F;      // E8M0 127 = 2^0 in every byte

// async global->LDS DMA, 16B/lane; LDS dst = wave-uniform base + lane*16.
// (R5/R11-R14-verified path.)
typedef __attribute__((address_space(1))) const unsigned int gu32;
typedef __attribute__((address_space(3))) unsigned int lu32;
__device__ __forceinline__ void gload16(const unsigned char* g, unsigned char* l) {
  __builtin_amdgcn_global_load_lds((gu32*)(uintptr_t)g, (lu32*)(uintptr_t)l, 16, 0, 0);
}

// ---------------------------------------------------------------------------
// Kernel 1: L2-normalize rows -> fp8 e4m3 (plain layout; the scaled MFMA's
// operand is 32 contiguous K-bytes per lane); init cbias / g_all / g_pos.
// ---------------------------------------------------------------------------
__global__ __launch_bounds__(256) void prep_kernel(const float* __restrict__ logits,
                                                   const float* __restrict__ labels,
                                                   const int* __restrict__ pad,
                                                   unsigned char* __restrict__ qb,
                                                   unsigned char* __restrict__ kb,
                                                   float* __restrict__ cbias,
                                                   float* __restrict__ g_all,
                                                   float* __restrict__ g_pos) {
  const int j = blockIdx.x * 256 + threadIdx.x;
  if (j < Nn) {
    cbias[j] = pad[j] ? 0.0f : -1e30f;
    g_all[j] = 0.0f;
    g_pos[j] = 0.0f;
  }

  const int gw   = (blockIdx.x * 256 + threadIdx.x) >> 6;
  const int lane = threadIdx.x & 63;
  const float* src;
  unsigned char* dst;
  int row;
  if (gw < Nn) { src = logits; dst = qb; row = gw; }
  else         { src = labels; dst = kb; row = gw - Nn; }

  const float4 v = *reinterpret_cast<const float4*>(src + (size_t)row * Dd + lane * 4);
  float ss = v.x * v.x + v.y * v.y + v.z * v.z + v.w * v.w;
#pragma unroll
  for (int m = 32; m >= 1; m >>= 1) ss += __shfl_xor(ss, m);
  const float scale = 1.0f / fmaxf(sqrtf(ss), 1e-12f);

  const __hip_fp8_e4m3 e0(v.x * scale);
  const __hip_fp8_e4m3 e1(v.y * scale);
  const __hip_fp8_e4m3 e2(v.z * scale);
  const __hip_fp8_e4m3 e3(v.w * scale);
  const unsigned int packed = (unsigned int)e0.__x |
                              ((unsigned int)e1.__x << 8) |
                              ((unsigned int)e2.__x << 16) |
                              ((unsigned int)e3.__x << 24);
  reinterpret_cast<unsigned int*>(dst + (size_t)row * Dd)[lane] = packed;
}

// ---------------------------------------------------------------------------
// Kernel 2: fused sim = Q K^T / tau + dual exp-sum epilogue, fp8 MX-MFMA.
// EXACT R14 structure (102.3 us best: 128x128 tile, K=128 scaled MFMA,
// DMA staging, swizzle slot = g ^ (r&7)) with ONE change:
// __launch_bounds__(256, 3) -> 3 resident blocks/CU (12 waves, was 8).
// Register need ~100-130 (R13 measured 68 + 32 for af[4]) fits the 170 cap.
// Spill canary: WRITE_SIZE (revert if >> 4 MB; R2's spill showed 381 MB).
// ---------------------------------------------------------------------------
__global__ __launch_bounds__(256, 3) void gemm_lse_kernel(const unsigned char* __restrict__ qb,
                                                          const unsigned char* __restrict__ kb,
                                                          const float* __restrict__ cbias,
                                                          const int* __restrict__ ad,
                                                          float* __restrict__ g_all,
                                                          float* __restrict__ g_pos) {
  __shared__ unsigned char smem[32768];  // As(16K) | Bs(16K); epilogue reuse
  unsigned char* As = smem;
  unsigned char* Bs = smem + 16384;
  float* redA = reinterpret_cast<float*>(smem);         // 128 x 32 partials
  float* redP = reinterpret_cast<float*>(smem) + 4096;  // 128 x 32 partials

  const int tid  = threadIdx.x;
  const int lane = tid & 63;
  const int w    = tid >> 6;
  const int wrow = (w >> 1) * 64;
  const int wcol = (w & 1) * 64;
  const int lq   = lane & 15;
  const int qd   = lane >> 4;
  const int rowBase = blockIdx.x * 128;
  const int colBase = blockIdx.y * 128;

  // staging constants (verified): wave w, iter i fills LDS rows
  // [w*32+i*8, +8); lane l -> row +(l>>3), logical 16B group (l&7)^(l>>3).
  const int srl = lane >> 3;
  const int cg  = (lane & 7) ^ srl;
  const unsigned char* gA0 = qb + (size_t)(rowBase + w * 32 + srl) * Dd + cg * 16;
  const unsigned char* gB0 = kb + (size_t)(colBase + w * 32 + srl) * Dd + cg * 16;

  f32x4 c[4][4];
#pragma unroll
  for (int mt = 0; mt < 4; ++mt)
#pragma unroll
    for (int nt = 0; nt < 4; ++nt)
      c[mt][nt] = (f32x4){0.f, 0.f, 0.f, 0.f};

  for (int kk = 0; kk < 2; ++kk) {
    const int kOff = kk * 128;  // byte offset into the 256 B row
    __syncthreads();  // prior MFMA phase done reading LDS
#pragma unroll
    for (int i = 0; i < 4; ++i) {
      gload16(gA0 + (size_t)i * 8 * Dd + kOff, &As[(w * 32 + i * 8) * 128]);
      gload16(gB0 + (size_t)i * 8 * Dd + kOff, &Bs[(w * 32 + i * 8) * 128]);
    }
    __syncthreads();  // drains vmcnt (DMA) before fragment reads

    const int g0 = qd << 1;  // lane's first 16B group (K bytes qd*32..+15)
    v8i af[4];
#pragma unroll
    for (int mt = 0; mt < 4; ++mt) {
      const int r = wrow + mt * 16 + lq;
      const i32x4 lo = *reinterpret_cast<const i32x4*>(&As[r * 128 + ((g0 ^ (r & 7)) << 4)]);
      const i32x4 hi = *reinterpret_cast<const i32x4*>(&As[r * 128 + (((g0 + 1) ^ (r & 7)) << 4)]);
      af[mt] = (v8i){lo.x, lo.y, lo.z, lo.w, hi.x, hi.y, hi.z, hi.w};
    }
#pragma unroll
    for (int nt = 0; nt < 4; ++nt) {
      const int r = wcol + nt * 16 + lq;
      const i32x4 lo = *reinterpret_cast<const i32x4*>(&Bs[r * 128 + ((g0 ^ (r & 7)) << 4)]);
      const i32x4 hi = *reinterpret_cast<const i32x4*>(&Bs[r * 128 + (((g0 + 1) ^ (r & 7)) << 4)]);
      const v8i bfq = (v8i){lo.x, lo.y, lo.z, lo.w, hi.x, hi.y, hi.z, hi.w};
#pragma unroll
      for (int mt = 0; mt < 4; ++mt)
        c[mt][nt] = __builtin_amdgcn_mfma_scale_f32_16x16x128_f8f6f4(
            af[mt], bfq, c[mt][nt], 0, 0, 0, SCALE1, 0, SCALE1);
    }
  }

  // ---- epilogue (R6/R11-R14-identical) ----
  float colB[4];
  int colAd[4];
#pragma unroll
  for (int nt = 0; nt < 4; ++nt) {
    const int col = colBase + wcol + nt * 16 + lq;
    colB[nt]  = SIM_BIAS + cbias[col];
    colAd[nt] = ad[col];
  }

  __syncthreads();  // all waves done with As/Bs before reuse as partials

  const int idx = (w & 1) * 16 + lq;   // 32 partials per row
  const int g   = idx >> 2;
  const int gi  = idx & 3;

#pragma unroll
  for (int mt = 0; mt < 4; ++mt) {
#pragma unroll
    for (int r = 0; r < 4; ++r) {
      const int row   = wrow + mt * 16 + qd * 4 + r;
      const int rowAd = ad[rowBase + row];
      float a = 0.f, p = 0.f;
#pragma unroll
      for (int nt = 0; nt < 4; ++nt) {
        const float e = __builtin_amdgcn_exp2f(fmaf(c[mt][nt][r], SIM_SCALE, colB[nt]));
        a += e;
        p += (colAd[nt] == rowAd) ? e : 0.f;
      }
      const int off = row * 32 + ((g ^ (row & 7)) << 2) + gi;
      redA[off] = a;
      redP[off] = p;
    }
  }
  __syncthreads();

  if (tid < 128) {
    const int row = tid;
    float a = 0.f, p = 0.f;
#pragma unroll
    for (int gg = 0; gg < 8; ++gg) {
      const int off = row * 32 + ((gg ^ (row & 7)) << 2);
      const f32x4 va = *reinterpret_cast<const f32x4*>(&redA[off]);
      const f32x4 vp = *reinterpret_cast<const f32x4*>(&redP[off]);
      a += (va[0] + va[1]) + (va[2] + va[3]);
      p += (vp[0] + vp[1]) + (vp[2] + vp[3]);
    }
    atomicAdd(&g_all[rowBase + row], a);
    atomicAdd(&g_pos[rowBase + row], p);
  }
}

// ---------------------------------------------------------------------------
// Kernel 3: loss = mean over valid rows of log(g_all) - log(g_pos).
// ---------------------------------------------------------------------------
__global__ __launch_bounds__(1024) void reduce_kernel(const float* __restrict__ g_all,
                                                      const float* __restrict__ g_pos,
                                                      const int* __restrict__ pad,
                                                      float* __restrict__ out) {
  __shared__ float sS[16], sC[16];
  const int t = threadIdx.x;
  float s = 0.f, c = 0.f;
  const float4* ga4 = (const float4*)g_all;
  const float4* gp4 = (const float4*)g_pos;
  const int4*   pd4 = (const int4*)pad;
  for (int i = t; i < Nn / 4; i += 1024) {
    const float4 ga = ga4[i];
    const float4 gp = gp4[i];
    const int4   pd = pd4[i];
    if (pd.x) { s += __logf(ga.x) - __logf(gp.x); c += 1.f; }
    if (pd.y) { s += __logf(ga.y) - __logf(gp.y); c += 1.f; }
    if (pd.z) { s += __logf(ga.z) - __logf(gp.z); c += 1.f; }
    if (pd.w) { s += __logf(ga.w) - __logf(gp.w); c += 1.f; }
  }
#pragma unroll
  for (int m = 32; m >= 1; m >>= 1) {
    s += __shfl_xor(s, m);
    c += __shfl_xor(c, m);
  }
  if ((t & 63) == 0) { sS[t >> 6] = s; sC[t >> 6] = c; }
  __syncthreads();
  if (t == 0) {
    float S = 0.f, C = 0.f;
#pragma unroll
    for (int i = 0; i < 16; ++i) { S += sS[i]; C += sC[i]; }
    out[0] = S / fmaxf(C, 1.0f);
  }
}

extern "C" void kernel_launch(void* const* d_in, const int* in_sizes, int n_in,
                              void* d_out, int out_size, void* d_ws, size_t ws_size,
                              hipStream_t stream) {
  const float* logits = (const float*)d_in[0];
  const float* labels = (const float*)d_in[1];
  const int*   pad    = (const int*)d_in[2];
  const int*   ad     = (const int*)d_in[3];

  char* ws = (char*)d_ws;
  unsigned char* qb = (unsigned char*)(ws);             // 2 MiB (fp8)
  unsigned char* kb = (unsigned char*)(ws + 2097152);   // 2 MiB (fp8)
  float*  cb   = (float*)(ws + 4194304);                // 32 KiB
  float*  gAll = (float*)(ws + 4227072);                // 32 KiB
  float*  gPos = (float*)(ws + 4259840);                // 32 KiB
  float*  out  = (float*)d_out;

  prep_kernel<<<4096, 256, 0, stream>>>(logits, labels, pad, qb, kb, cb, gAll, gPos);
  gemm_lse_kernel<<<dim3(64, 64), 256, 0, stream>>>(qb, kb, cb, ad, gAll, gPos);
  reduce_kernel<<<1, 1024, 0, stream>>>(gAll, gPos, pad, out);
}